// Round 4
// baseline (478.454 us; speedup 1.0000x reference)
//
#include <hip/hip_runtime.h>
#include <hip/hip_bf16.h>

typedef float f32x4 __attribute__((ext_vector_type(4)));
typedef short s16x8 __attribute__((ext_vector_type(8)));

#define SMEM_BYTES 24576   // max over variants -> 6 WGs/CU

__device__ __forceinline__ unsigned short f32_to_bf16(float f){
    union { float f; unsigned u; } v; v.f = f;
    unsigned r = v.u + 0x7fffu + ((v.u >> 16) & 1u);   // RNE
    return (unsigned short)(r >> 16);
}
__device__ __forceinline__ unsigned pack2(float a, float b){
    float2 t; t.x = a; t.y = b;
    __hip_bfloat162 h = __float22bfloat162_rn(t);      // v_cvt_pk_bf16_f32
    union { __hip_bfloat162 h; unsigned u; } c; c.h = h;
    return c.u;
}

// ---------- W pre-convert: wbf[w][d][c] = bf16(W[d][c] + (d==c)) -------------
__global__ __launch_bounds__(256)
void wconv_kernel(const float* __restrict__ W0p, const float* __restrict__ W0m,
                  const float* __restrict__ W1p, const float* __restrict__ W1m,
                  const float* __restrict__ W2p, const float* __restrict__ W2m,
                  unsigned short* __restrict__ wbf)
{
    const int idx = blockIdx.x * 256 + threadIdx.x;   // 384*256 = 98304
    const int w  = idx >> 14;
    const int rc = idx & 16383;
    const float* Wp;
    switch (w) {
        case 0: Wp = W0p; break;  case 1: Wp = W0m; break;
        case 2: Wp = W1p; break;  case 3: Wp = W1m; break;
        case 4: Wp = W2p; break;  default: Wp = W2m; break;
    }
    const float v = Wp[rc] + (((rc >> 7) == (rc & 127)) ? 1.0f : 0.0f);
    wbf[idx] = f32_to_bf16(v);
}

// ---------- l = 1,2 body: A = x rows (n,m), B = (W+I) cols -------------------
// src/dst pre-offset to this block's column base. tile covers NT nodes.
template<int ML, int NT>
__device__ __forceinline__
void lx_body(const float* __restrict__ src0, const unsigned short* __restrict__ wb,
             float* __restrict__ dst0, int tile, char* smem)
{
    constexpr int BLK   = 128 * ML;            // floats per node-block
    constexpr int RROWS = NT * ML;             // real rows: 40 / 48
    constexpr int RTC   = (RROWS + 15) / 16;   // MFMA row-tiles: 3 / 3
    constexpr int H     = (RTC + 1) / 2;       // tiles per wave-half: 2
    constexpr int LDSS  = 136;                 // bf16 elems per lin row (272 B)
    constexpr int QPT   = NT * 32 / 256;       // channel-quads per thread: 1 / 2
    constexpr int ITER  = NT * BLK / 1024;     // flush float4 iters: 5 / 6

    unsigned short* lin  = (unsigned short*)smem;
    float*          lout = (float*)smem;

    const size_t nbase = (size_t)tile * NT;
    const int tid = threadIdx.x;
    const int wv  = tid >> 6, ln = tid & 63;
    const int l16 = ln & 15,  lhi = ln >> 4;

    // ---- stage: quad of 4 channels x all m per thread-iter -> bf16 rows
    const float* src = src0 + nbase * 2304;
    #pragma unroll
    for (int i = 0; i < QPT; ++i) {
        const int q  = i * 256 + tid;
        const int nl = q >> 5;
        const int c4 = (q & 31) * 4;
        const float* p = src + (size_t)nl * 2304 + c4 * ML;
        float v[4 * ML];
        #pragma unroll
        for (int j = 0; j < ML; ++j) {
            const float4 t = *reinterpret_cast<const float4*>(p + j * 4);
            v[j*4+0] = t.x; v[j*4+1] = t.y; v[j*4+2] = t.z; v[j*4+3] = t.w;
        }
        #pragma unroll
        for (int mm = 0; mm < ML; ++mm) {
            uint2 pk;
            pk.x = pack2(v[mm], v[mm + ML]);
            pk.y = pack2(v[mm + 2*ML], v[mm + 3*ML]);
            *reinterpret_cast<uint2*>(&lin[(nl * ML + mm) * LDSS + c4]) = pk;
        }
    }
    __syncthreads();

    // ---- MFMA: wave = (tile-half th, col-half ch)
    const int th = wv >> 1, ch = wv & 1;
    const int t0 = th * H;

    f32x4 acc[H][4];
    #pragma unroll
    for (int rt = 0; rt < H; ++rt)
        #pragma unroll
        for (int tf = 0; tf < 4; ++tf) acc[rt][tf] = (f32x4){0.f,0.f,0.f,0.f};

    #pragma unroll
    for (int s = 0; s < 4; ++s) {
        const int k0 = s * 32 + lhi * 8;
        s16x8 bf[4];
        #pragma unroll
        for (int tf = 0; tf < 4; ++tf)
            bf[tf] = *reinterpret_cast<const s16x8*>(wb + (ch * 64 + tf * 16 + l16) * 128 + k0);
        #pragma unroll
        for (int rt = 0; rt < H; ++rt) {
            if (t0 + rt < RTC) {
                const s16x8 af = *reinterpret_cast<const s16x8*>(
                    &lin[((t0 + rt) * 16 + l16) * LDSS + k0]);
                #pragma unroll
                for (int tf = 0; tf < 4; ++tf)
                    acc[rt][tf] = __builtin_amdgcn_mfma_f32_16x16x32_bf16(af, bf[tf], acc[rt][tf], 0, 0, 0);
            }
        }
    }
    __syncthreads();   // lin dead; lout takes over smem

    // ---- scatter acc -> lout in output (interleaved) layout; guard pad rows
    #pragma unroll
    for (int rt = 0; rt < H; ++rt) {
        if (t0 + rt < RTC) {
            #pragma unroll
            for (int tf = 0; tf < 4; ++tf) {
                const int col = ch * 64 + tf * 16 + l16;
                #pragma unroll
                for (int j = 0; j < 4; ++j) {
                    const int row = (t0 + rt) * 16 + lhi * 4 + j;
                    if (row < RROWS) {
                        const int nl = row / ML;
                        const int mm = row - nl * ML;
                        lout[nl * BLK + col * ML + mm] = acc[rt][tf][j];
                    }
                }
            }
        }
    }
    __syncthreads();

    // ---- flush: contiguous float4 stores
    float* dst = dst0 + nbase * 2304;
    #pragma unroll
    for (int i = 0; i < ITER; ++i) {
        const int f  = (i * 256 + tid) * 4;
        const int nl = f / BLK;
        const int rr = f - nl * BLK;
        *reinterpret_cast<float4*>(dst + (size_t)nl * 2304 + rr) =
            *reinterpret_cast<const float4*>(&lout[f]);
    }
}

// ---------- l = 0 body: operand-swapped, direct coalesced stores -------------
__device__ __forceinline__
void l0_body(const float* __restrict__ x, const unsigned short* __restrict__ wbf,
             float* __restrict__ out, int tile, char* smem)
{
    constexpr int LDSS = 264;                       // 528 B rows
    unsigned short* lin = (unsigned short*)smem;    // 32*264*2 = 16.9 KB

    const size_t nbase = (size_t)tile * 32;
    const int tid = threadIdx.x;
    const int wv  = tid >> 6, ln = tid & 63;
    const int l16 = ln & 15,  lhi = ln >> 4;

    const float* src = x + nbase * 2304;
    #pragma unroll
    for (int i = 0; i < 8; ++i) {
        const int f  = i * 1024 + tid * 4;
        const int nl = f >> 8, c = f & 255;
        const float4 v = *reinterpret_cast<const float4*>(src + (size_t)nl * 2304 + c);
        uint2 p; p.x = pack2(v.x, v.y); p.y = pack2(v.z, v.w);
        *reinterpret_cast<uint2*>(&lin[nl * LDSS + c]) = p;
    }
    __syncthreads();

    const int b     = wv >> 1;            // parity (0e / 0o)
    const int dbase = (wv & 1) * 64;
    const unsigned short* wb = wbf + b * 16384;

    f32x4 acc[2][4];
    #pragma unroll
    for (int nt = 0; nt < 2; ++nt)
        #pragma unroll
        for (int dt = 0; dt < 4; ++dt) acc[nt][dt] = (f32x4){0.f,0.f,0.f,0.f};

    #pragma unroll
    for (int s = 0; s < 4; ++s) {
        const int k0 = s * 32 + lhi * 8;
        s16x8 af[4];
        #pragma unroll
        for (int dt = 0; dt < 4; ++dt)
            af[dt] = *reinterpret_cast<const s16x8*>(wb + (dbase + dt * 16 + l16) * 128 + k0);
        #pragma unroll
        for (int nt = 0; nt < 2; ++nt) {
            const s16x8 bfv = *reinterpret_cast<const s16x8*>(
                &lin[(nt * 16 + l16) * LDSS + b * 128 + k0]);
            #pragma unroll
            for (int dt = 0; dt < 4; ++dt)
                acc[nt][dt] = __builtin_amdgcn_mfma_f32_16x16x32_bf16(af[dt], bfv, acc[nt][dt], 0, 0, 0);
        }
    }

    // store: lane l16 = node, reg quad = 4 consecutive d -> coalesced float4
    #pragma unroll
    for (int nt = 0; nt < 2; ++nt) {
        float* dst = out + (nbase + nt * 16 + l16) * 2304 + b * 128 + dbase + lhi * 4;
        #pragma unroll
        for (int dt = 0; dt < 4; ++dt) {
            float4 v; v.x = acc[nt][dt][0]; v.y = acc[nt][dt][1];
                      v.z = acc[nt][dt][2]; v.w = acc[nt][dt][3];
            *reinterpret_cast<float4*>(dst + dt * 16) = v;
        }
    }
}

// ---------- fused kernel: 13-way proportional interleave of variants ---------
// bucket pattern: 8x lx5(NT=8) : 4x lx3(NT=16) : 1x l0(NT=32)
// grid = 13 * 3125 = 40625; covers N=100000 exactly for all six blocks.
__global__ __launch_bounds__(256)
void fused_kernel(const float* __restrict__ x, const unsigned short* __restrict__ wbf,
                  float* __restrict__ out)
{
    __shared__ __attribute__((aligned(16))) char smem[SMEM_BYTES];
    const int bucket = blockIdx.x / 13;
    const int r      = blockIdx.x - bucket * 13;

    if (r < 8) {                                    // l=2 (2e:1024, 2o:1664)
        const int idx    = bucket * 8 + r;          // [0, 25000)
        const int parity = idx & 1;
        const int tile   = idx >> 1;                // [0, 12500)
        const int off    = parity ? 1664 : 1024;
        lx_body<5, 8>(x + off, wbf + (size_t)(4 + parity) * 16384, out + off, tile, smem);
    } else if (r < 12) {                            // l=1 (1e:256, 1o:640)
        const int idx    = bucket * 4 + (r - 8);    // [0, 12500)
        const int parity = idx & 1;
        const int tile   = idx >> 1;                // [0, 6250)
        const int off    = parity ? 640 : 256;
        lx_body<3, 16>(x + off, wbf + (size_t)(2 + parity) * 16384, out + off, tile, smem);
    } else {                                        // l=0 (0e:0, 0o:128)
        l0_body(x, wbf, out, bucket, smem);         // bucket in [0, 3125)
    }
}

extern "C" void kernel_launch(void* const* d_in, const int* in_sizes, int n_in,
                              void* d_out, int out_size, void* d_ws, size_t ws_size,
                              hipStream_t stream) {
    const float* x   = (const float*)d_in[0];
    const float* W0p = (const float*)d_in[1];
    const float* W0m = (const float*)d_in[2];
    const float* W1p = (const float*)d_in[3];
    const float* W1m = (const float*)d_in[4];
    const float* W2p = (const float*)d_in[5];
    const float* W2m = (const float*)d_in[6];
    float* out = (float*)d_out;
    unsigned short* wbf = (unsigned short*)d_ws;   // 6*128*128 bf16 = 196.6 KB

    wconv_kernel<<<384, 256, 0, stream>>>(W0p, W0m, W1p, W1m, W2p, W2m, wbf);
    fused_kernel<<<40625, 256, 0, stream>>>(x, wbf, out);
}